// Round 7
// baseline (353.709 us; speedup 1.0000x reference)
//
#include <hip/hip_runtime.h>
#include <hip/hip_bf16.h>
#include <math.h>

// AdaptGNN: B=8, N=2048, D=H=128, 3 layers.
// R11: agg -> 256-thr blocks (4 waves, p-block 32), 72KB LDS, grid 512 =
// 2 blocks/CU: two independent barrier domains per CU so one block's
// compute fills the other's barrier/latency stalls (R10 proved agg is
// latency-bound, not work-bound: removing work was neutral; all pipes <10%).
// Also: shfl_xor(32) -> v_permlane32_swap_b32 (VALU, off the DS pipe);
// linear's tn store via LDS roundtrip (coalesced b128 instead of 32
// scattered b16 global stores per thread).

typedef __attribute__((ext_vector_type(8)))  short bf16x8;
typedef __attribute__((ext_vector_type(4)))  short bf16x4;
typedef __attribute__((ext_vector_type(4)))  float f32x4;
typedef __attribute__((ext_vector_type(16))) float f32x16;
typedef __attribute__((ext_vector_type(2)))  unsigned u32x2;

static constexpr int kB = 8, kN = 2048, kH = 128;

static __device__ __forceinline__ ushort bf16bits(float f) {
    __hip_bfloat16 hb = __float2bfloat16(f);
    return *reinterpret_cast<ushort*>(&hb);
}
static __device__ __forceinline__ unsigned pk2(float lo, float hi) {
    return (unsigned)bf16bits(lo) | ((unsigned)bf16bits(hi) << 16);
}
static __device__ __forceinline__ float bf2f_lo(unsigned u) {
    unsigned v = u << 16; float f; __builtin_memcpy(&f, &v, 4); return f;
}
static __device__ __forceinline__ float bf2f_hi(unsigned u) {
    unsigned v = u & 0xffff0000u; float f; __builtin_memcpy(&f, &v, 4); return f;
}

// LDS-visibility fence + raw barrier: does NOT drain vmcnt (prefetch loads
// stay in flight; compiler inserts counted vmcnt at their uses).
#define LDS_BARRIER()                                          \
    do {                                                       \
        asm volatile("s_waitcnt lgkmcnt(0)" ::: "memory");     \
        __builtin_amdgcn_s_barrier();                          \
        __builtin_amdgcn_sched_barrier(0);                     \
    } while (0)

// ---------------- x -> bf16 ----------------
__global__ __launch_bounds__(256) void cvt_bf16_kernel(
    const float* __restrict__ src, ushort* __restrict__ dst, int n4)
{
    int i = blockIdx.x * 256 + threadIdx.x;
    if (i >= n4) return;
    float4 v = ((const float4*)src)[i];
    bf16x4 o;
    o[0] = (short)bf16bits(v.x); o[1] = (short)bf16bits(v.y);
    o[2] = (short)bf16bits(v.z); o[3] = (short)bf16bits(v.w);
    ((bf16x4*)dst)[i] = o;
}

// WT[l][c][d] = bf16(W_l[d][c]) — all 3 layers in one launch
__global__ __launch_bounds__(256) void cvt_wT_kernel(
    const float* __restrict__ W0, const float* __restrict__ W1,
    const float* __restrict__ W2, ushort* __restrict__ WT)
{
    const float* W = blockIdx.y == 0 ? W0 : (blockIdx.y == 1 ? W1 : W2);
    int i = blockIdx.x * 256 + threadIdx.x;  // 0..16383
    int d = i >> 7, c = i & 127;
    WT[(size_t)blockIdx.y * kH * kH + c * kH + d] = bf16bits(W[d * kH + c]);
}

// ---------------- linear (bf16 MFMA) + row-norm; writes tn (normalized) + tT (raw) ----------------
__global__ __launch_bounds__(256) void linear_tr_kernel(
    const ushort* __restrict__ h16, const ushort* __restrict__ WT,
    const float* __restrict__ bias, ushort* __restrict__ tn16,
    ushort* __restrict__ tT16)
{
    __shared__ float ssb[64][2];
    __shared__ ushort tr[128 * 72];    // [c][p_local], 144B rows (odd-16B rotate)
    __shared__ ushort trn[64 * 136];   // [p_local][c], 272B rows (odd-16B rotate)

    const int tid = threadIdx.x, lane = tid & 63, wid = tid >> 6;
    const int wr = wid >> 1, wc = wid & 1, quad = lane >> 4, l16 = lane & 15;
    const int rowbase = blockIdx.x * 64;           // global BN row
    const int b = rowbase / kN, q0 = rowbase % kN; // batch / in-batch row

    f32x4 acc[2][4];
#pragma unroll
    for (int i = 0; i < 2; ++i)
#pragma unroll
        for (int ct = 0; ct < 4; ++ct) acc[i][ct] = (f32x4){0.f, 0.f, 0.f, 0.f};

#pragma unroll
    for (int k = 0; k < 4; ++k) {
        bf16x8 Af[2], Bf[4];
#pragma unroll
        for (int i = 0; i < 2; ++i)
            Af[i] = *(const bf16x8*)&h16[(size_t)(rowbase + wr * 32 + i * 16 + l16) * kH + k * 32 + quad * 8];
#pragma unroll
        for (int ct = 0; ct < 4; ++ct)
            Bf[ct] = *(const bf16x8*)&WT[(size_t)(wc * 64 + ct * 16 + l16) * kH + k * 32 + quad * 8];
#pragma unroll
        for (int i = 0; i < 2; ++i)
#pragma unroll
            for (int ct = 0; ct < 4; ++ct)
                acc[i][ct] = __builtin_amdgcn_mfma_f32_16x16x32_bf16(Af[i], Bf[ct], acc[i][ct], 0, 0, 0);
    }

    float bsr[4];
#pragma unroll
    for (int ct = 0; ct < 4; ++ct) bsr[ct] = bias[wc * 64 + ct * 16 + l16];

    f32x4 ss[2] = {(f32x4){0,0,0,0}, (f32x4){0,0,0,0}};
#pragma unroll
    for (int i = 0; i < 2; ++i)
#pragma unroll
        for (int ct = 0; ct < 4; ++ct)
#pragma unroll
            for (int r = 0; r < 4; ++r) {
                float v = acc[i][ct][r] + bsr[ct];
                acc[i][ct][r] = v;
                ss[i][r] += v * v;
            }
#pragma unroll
    for (int step = 1; step < 16; step <<= 1)
#pragma unroll
        for (int i = 0; i < 2; ++i)
#pragma unroll
            for (int r = 0; r < 4; ++r) ss[i][r] += __shfl_xor(ss[i][r], step);

    if (l16 == 0)
#pragma unroll
        for (int i = 0; i < 2; ++i)
#pragma unroll
            for (int r = 0; r < 4; ++r)
                ssb[wr * 32 + i * 16 + quad * 4 + r][wc] = ss[i][r];
    __syncthreads();

    // per-thread inv-norm for its 8 rows
    float invr[2][4];
#pragma unroll
    for (int i = 0; i < 2; ++i)
#pragma unroll
        for (int r = 0; r < 4; ++r) {
            const int pl = wr * 32 + i * 16 + quad * 4 + r;
            float s2 = ssb[pl][0] + ssb[pl][1];
            invr[i][r] = 1.f / fmaxf(sqrtf(s2), 1e-12f);
        }

    // LDS tiles: tr (raw, c-major) + trn (normalized, p-major)
#pragma unroll
    for (int i = 0; i < 2; ++i)
#pragma unroll
        for (int ct = 0; ct < 4; ++ct)
#pragma unroll
            for (int r = 0; r < 4; ++r) {
                const int pl = wr * 32 + i * 16 + quad * 4 + r;
                const int c = wc * 64 + ct * 16 + l16;
                const float v = acc[i][ct][r];
                tr[c * 72 + pl] = bf16bits(v);
                trn[pl * 136 + c] = bf16bits(v * invr[i][r]);
            }
    __syncthreads();

    // coalesced tT writeout: 128 c-rows x 64 q (raw t)
    ushort* tTb = tT16 + (size_t)b * kH * kN;
#pragma unroll
    for (int it = 0; it < 4; ++it) {
        int idx = tid + 256 * it;           // 0..1023
        int c = idx >> 3, ch = idx & 7;
        bf16x8 v = *(const bf16x8*)&tr[c * 72 + ch * 8];
        *(bf16x8*)&tTb[(size_t)c * kN + q0 + ch * 8] = v;
    }
    // coalesced tn writeout: 64 p-rows x 128 c (normalized)
#pragma unroll
    for (int it = 0; it < 4; ++it) {
        int idx = tid + 256 * it;           // 0..1023
        int p = idx >> 4, ch = idx & 15;
        bf16x8 v = *(const bf16x8*)&trn[p * 136 + ch * 8];
        *(bf16x8*)&tn16[(size_t)(rowbase + p) * kH + ch * 8] = v;
    }
}

// ---------------- fused aggregation: 2 blocks/CU, LDS-staged, in-register S'->O ----------------
// 256 thr = 4 waves (wq = wid: q 32-quarters of the 128 q-tile; all waves
// share the block's 32 p-rows). grid (8 batches, 64 p-blocks) = 512 blocks
// = 2/CU (LDS 72KB). Single-buffered tiles, 2 raw barriers/iter; the
// co-resident block fills convergence/latency stalls.
__global__ __launch_bounds__(256, 2) void agg_kernel(
    const ushort* __restrict__ tn, const ushort* __restrict__ tT,
    const float* __restrict__ ew,
    ushort* __restrict__ hout, float* __restrict__ fout, int last)
{
    __shared__ char lds[73728];  // TQ 32K | TT 32K | ew 4x2K

    const int b = blockIdx.x, pbase = blockIdx.y * 32;
    const int tid = threadIdx.x, lane = tid & 63, wq = tid >> 6;
    const int l31 = lane & 31, h = lane >> 5;

    const ushort* tb  = tn + (size_t)b * kN * kH;
    const ushort* tTb = tT + (size_t)b * kH * kN;
    const float*  ewb = ew + (size_t)b * kN * kN;

    char* TQ   = lds;                       // [128 q][256B], swz ((q&15)<<4)
    char* TT   = lds + 32768;               // [128 c][256B], swz ((c&15)<<4)
    char* myEw = lds + 65536 + wq * 2048;   // [32 p][64B] bf16, swz ((p&7)<<3)

    // tP (B-operand of swapped S, normalized rows): one-time scattered load
    bf16x8 tP[8];
#pragma unroll
    for (int m = 0; m < 8; ++m)
        tP[m] = *(const bf16x8*)&tb[(size_t)(pbase + l31) * kH + m * 16 + h * 8];

    f32x16 oacc[4];
#pragma unroll
    for (int ct = 0; ct < 4; ++ct)
#pragma unroll
        for (int r = 0; r < 16; ++r) oacc[ct][r] = 0.f;

    // staging maps: TQ/TT 16 thr/row (16B chunks), 16 rows/pass x 8 passes
    const int sgRow = tid >> 4, sgCh = tid & 15;
    // ew map: 8 lanes/row (f32x4), 8 rows/pass x 4 passes (32p x 32q per wave)
    const int ewR = lane >> 3, ewQ = lane & 7;

    bf16x8 rQ[8], rT[8];
    f32x4 eC[4];

    auto prefetch = [&](int qb) {
#pragma unroll
        for (int j = 0; j < 8; ++j) {
            rQ[j] = *(const bf16x8*)&tb[(size_t)(qb + sgRow + 16 * j) * kH + sgCh * 8];
            rT[j] = *(const bf16x8*)&tTb[(size_t)(sgRow + 16 * j) * kN + qb + sgCh * 8];
        }
#pragma unroll
        for (int j = 0; j < 4; ++j)
            eC[j] = *(const f32x4*)&ewb[(size_t)(pbase + 8 * j + ewR) * kN + qb + wq * 32 + ewQ * 4];
    };
    prefetch(0);

    // scale S'[32p x 32q] by ew, pack bf16, half-swap (permlane) -> 2 A-frags
    auto buildFrags = [&](const f32x16& sa, const f32x16& sb, bf16x8* out2) {
        float sv[16];
#pragma unroll
        for (int g = 0; g < 4; ++g) {
            u32x2 ev = *(const u32x2*)&myEw[l31 * 64 + ((16 * g + 8 * h) ^ ((l31 & 7) << 3))];
            sv[4 * g + 0] = (sa[4 * g + 0] + sb[4 * g + 0]) * bf2f_lo(ev[0]);
            sv[4 * g + 1] = (sa[4 * g + 1] + sb[4 * g + 1]) * bf2f_hi(ev[0]);
            sv[4 * g + 2] = (sa[4 * g + 2] + sb[4 * g + 2]) * bf2f_lo(ev[1]);
            sv[4 * g + 3] = (sa[4 * g + 3] + sb[4 * g + 3]) * bf2f_hi(ev[1]);
        }
#pragma unroll
        for (int kk = 0; kk < 2; ++kk) {
            const int e0 = kk * 8;
            unsigned a0 = pk2(sv[e0 + 0], sv[e0 + 1]);
            unsigned a1 = pk2(sv[e0 + 2], sv[e0 + 3]);
            unsigned b0 = pk2(sv[e0 + 4], sv[e0 + 5]);
            unsigned b1 = pk2(sv[e0 + 6], sv[e0 + 7]);
            // v_permlane32_swap: a' = [a_lo | b_lo], b' = [a_hi | b_hi]
            asm("v_permlane32_swap_b32 %0, %1" : "+v"(a0), "+v"(b0));
            asm("v_permlane32_swap_b32 %0, %1" : "+v"(a1), "+v"(b1));
            union { unsigned u[4]; bf16x8 v; } U;
            U.u[0] = a0;   // q-pair (8h+0, 8h+1)
            U.u[1] = a1;   // q-pair (8h+2, 8h+3)
            U.u[2] = b0;   // q-pair (8h+4, 8h+5)
            U.u[3] = b1;   // q-pair (8h+6, 8h+7)
            out2[kk] = U.v;
        }
    };

    for (int it = 0; it < 16; ++it) {
        const int qb = it * 128;

        // ---- publish staged tile (waits counted vmcnt on prefetch regs) ----
#pragma unroll
        for (int j = 0; j < 8; ++j) {
            const int row = sgRow + 16 * j;
            const int swz = (row & 15) << 4;
            *(bf16x8*)&TQ[row * 256 + ((sgCh * 16) ^ swz)] = rQ[j];
            *(bf16x8*)&TT[row * 256 + ((sgCh * 16) ^ swz)] = rT[j];
        }
#pragma unroll
        for (int j = 0; j < 4; ++j) {
            const int row = 8 * j + ewR;
            u32x2 w;
            w[0] = pk2(eC[j][0], eC[j][1]);
            w[1] = pk2(eC[j][2], eC[j][3]);
            *(u32x2*)&myEw[row * 64 + ((ewQ * 8) ^ ((row & 7) << 3))] = w;
        }

        // ---- issue next tile's globals (in flight across barrier+compute) ----
        if (it < 15) prefetch(qb + 128);

        LDS_BARRIER();  // #1: tiles visible

        // ---- S-phase: s[q=32(wq)][p=32] = tnQ . tnP^T over d=128 ----
        f32x16 s0a, s0b;
#pragma unroll
        for (int r = 0; r < 16; ++r) { s0a[r] = 0.f; s0b[r] = 0.f; }
        const int qrow = wq * 32 + l31;
        const int qswz = (qrow & 15) << 4;
#pragma unroll
        for (int m = 0; m < 8; ++m) {
            bf16x8 a = *(const bf16x8*)&TQ[qrow * 256 + ((m * 32 + 16 * h) ^ qswz)];
            if (m & 1) s0b = __builtin_amdgcn_mfma_f32_32x32x16_bf16(a, tP[m], s0b, 0, 0, 0);
            else       s0a = __builtin_amdgcn_mfma_f32_32x32x16_bf16(a, tP[m], s0a, 0, 0, 0);
        }

        bf16x8 aw[2];
        buildFrags(s0a, s0b, aw);

        // ---- O-phase: oacc[p][c] += S'[32p x 32q] @ t[32q x 128c] ----
#pragma unroll
        for (int kkt = 0; kkt < 2; ++kkt) {
#pragma unroll
            for (int ct = 0; ct < 4; ++ct) {
                const int crow = 32 * ct + l31;
                bf16x8 Bf = *(const bf16x8*)&TT[crow * 256 +
                              ((wq * 64 + kkt * 32 + 16 * h) ^ ((crow & 15) << 4))];
                oacc[ct] = __builtin_amdgcn_mfma_f32_32x32x16_bf16(aw[kkt], Bf, oacc[ct], 0, 0, 0);
            }
        }
        LDS_BARRIER();  // #2: all reads of this tile done -> next publish safe
    }

    // ---- epilogue: reduce 4 wq partials in LDS (reuses TQ region), store ----
    float* OL = (float*)lds;   // [32][128] f32 = 16 KB
#pragma unroll
    for (int w = 0; w < 4; ++w) {
        if (wq == w) {
#pragma unroll
            for (int ct = 0; ct < 4; ++ct)
#pragma unroll
                for (int r = 0; r < 16; ++r) {
                    const int pl = (r & 3) + 8 * (r >> 2) + 4 * h;
                    const int idx = pl * 128 + 32 * ct + l31;
                    if (w == 0) OL[idx] = oacc[ct][r];
                    else        OL[idx] += oacc[ct][r];
                }
        }
        __syncthreads();
    }

    {
        const int p = tid >> 3, cb = (tid & 7) * 16;
        const size_t gbase = (size_t)b * kN * kH + (size_t)(pbase + p) * kH + cb;
        if (!last) {
#pragma unroll
            for (int u = 0; u < 2; ++u) {
                bf16x8 o;
#pragma unroll
                for (int k = 0; k < 8; ++k)
                    o[k] = (short)bf16bits(fmaxf(OL[p * 128 + cb + u * 8 + k], 0.f));
                *(bf16x8*)&hout[gbase + u * 8] = o;
            }
        } else {
#pragma unroll
            for (int u = 0; u < 4; ++u) {
                f32x4 o;
#pragma unroll
                for (int k = 0; k < 4; ++k)
                    o[k] = OL[p * 128 + cb + u * 4 + k];
                *(f32x4*)&fout[gbase + u * 4] = o;
            }
        }
    }
}

extern "C" void kernel_launch(void* const* d_in, const int* in_sizes, int n_in,
                              void* d_out, int out_size, void* d_ws, size_t ws_size,
                              hipStream_t stream) {
    const float* x  = (const float*)d_in[0];
    const float* ew = (const float*)d_in[1];
    const float* W0 = (const float*)d_in[2];
    const float* b0 = (const float*)d_in[3];
    const float* W1 = (const float*)d_in[4];
    const float* b1 = (const float*)d_in[5];
    const float* W2 = (const float*)d_in[6];
    const float* b2 = (const float*)d_in[7];
    const float* bias[3] = {b0, b1, b2};

    const size_t nBNH = (size_t)kB * kN * kH;  // 2M
    ushort* h16  = (ushort*)d_ws;               // [B,N,H] bf16 (x, then relu h)
    ushort* tn16 = h16 + nBNH;                  // [B,N,H] bf16 normalized t
    ushort* tT16 = tn16 + nBNH;                 // [B,H,N] bf16 raw t, transposed
    ushort* WT   = tT16 + nBNH;                 // 3 x [H,D] bf16
    float*  out  = (float*)d_out;

    cvt_bf16_kernel<<<(int)(nBNH / 4 + 255) / 256, 256, 0, stream>>>(x, h16, (int)(nBNH / 4));
    cvt_wT_kernel<<<dim3(64, 3), 256, 0, stream>>>(W0, W1, W2, WT);

    for (int layer = 0; layer < 3; ++layer) {
        linear_tr_kernel<<<kB * kN / 64, 256, 0, stream>>>(
            h16, WT + (size_t)layer * kH * kH, bias[layer], tn16, tT16);
        agg_kernel<<<dim3(kB, kN / 32), 256, 0, stream>>>(
            tn16, tT16, ew, h16, out, layer == 2 ? 1 : 0);
    }
}

// Round 11
// 327.383 us; speedup vs baseline: 1.0804x; 1.0804x over previous
//
#include <hip/hip_runtime.h>
#include <hip/hip_bf16.h>
#include <math.h>

// AdaptGNN: B=8, N=2048, D=H=128, 3 layers.
// R15 = R13/R14 third attempt (both died as container-level failures with no
// pytest output; kernel re-audited for hang mechanisms: none found; R12's
// genuine fault DID produce a traceback, so DMA kernels run here).
// Defensive change only: LDS declared as typed __shared__ arrays instead of
// one char blob (clean addrspace(3) casts for global_load_lds).
// Structure: agg staged via global_load_lds (direct L2->LDS DMA, pre-swizzled
// per-lane source, linear LDS dest), double-buffered, 1 barrier/iter,
// in-register S'->O handoff (permlane32_swap), normalization folded into tn.

typedef __attribute__((ext_vector_type(8)))  short bf16x8;
typedef __attribute__((ext_vector_type(4)))  short bf16x4;
typedef __attribute__((ext_vector_type(4)))  float f32x4;
typedef __attribute__((ext_vector_type(16))) float f32x16;
typedef __attribute__((ext_vector_type(2)))  unsigned u32x2;

static constexpr int kB = 8, kN = 2048, kH = 128;

static __device__ __forceinline__ ushort bf16bits(float f) {
    __hip_bfloat16 hb = __float2bfloat16(f);
    return *reinterpret_cast<ushort*>(&hb);
}
static __device__ __forceinline__ unsigned pk2(float lo, float hi) {
    return (unsigned)bf16bits(lo) | ((unsigned)bf16bits(hi) << 16);
}
static __device__ __forceinline__ float bf2f_lo(unsigned u) {
    unsigned v = u << 16; float f; __builtin_memcpy(&f, &v, 4); return f;
}
static __device__ __forceinline__ float bf2f_hi(unsigned u) {
    unsigned v = u & 0xffff0000u; float f; __builtin_memcpy(&f, &v, 4); return f;
}

typedef __attribute__((address_space(1))) const unsigned gu32;
typedef __attribute__((address_space(3))) unsigned lu32;
static __device__ __forceinline__ void gload16(const void* g, void* l) {
    __builtin_amdgcn_global_load_lds((gu32*)g, (lu32*)l, 16, 0, 0);
}

// ---------------- x -> bf16 ----------------
__global__ __launch_bounds__(256) void cvt_bf16_kernel(
    const float* __restrict__ src, ushort* __restrict__ dst, int n4)
{
    int i = blockIdx.x * 256 + threadIdx.x;
    if (i >= n4) return;
    float4 v = ((const float4*)src)[i];
    bf16x4 o;
    o[0] = (short)bf16bits(v.x); o[1] = (short)bf16bits(v.y);
    o[2] = (short)bf16bits(v.z); o[3] = (short)bf16bits(v.w);
    ((bf16x4*)dst)[i] = o;
}

// WT[l][c][d] = bf16(W_l[d][c]) — all 3 layers in one launch
__global__ __launch_bounds__(256) void cvt_wT_kernel(
    const float* __restrict__ W0, const float* __restrict__ W1,
    const float* __restrict__ W2, ushort* __restrict__ WT)
{
    const float* W = blockIdx.y == 0 ? W0 : (blockIdx.y == 1 ? W1 : W2);
    int i = blockIdx.x * 256 + threadIdx.x;  // 0..16383
    int d = i >> 7, c = i & 127;
    WT[(size_t)blockIdx.y * kH * kH + c * kH + d] = bf16bits(W[d * kH + c]);
}

// ---------------- linear (bf16 MFMA) + row-norm; writes tn (normalized) + tT (raw) ----------------
__global__ __launch_bounds__(256) void linear_tr_kernel(
    const ushort* __restrict__ h16, const ushort* __restrict__ WT,
    const float* __restrict__ bias, ushort* __restrict__ tn16,
    ushort* __restrict__ tT16)
{
    __shared__ float ssb[64][2];
    __shared__ ushort tr[128 * 72];    // [c][p_local], 144B rows (odd-16B rotate)
    __shared__ ushort trn[64 * 136];   // [p_local][c], 272B rows (odd-16B rotate)

    const int tid = threadIdx.x, lane = tid & 63, wid = tid >> 6;
    const int wr = wid >> 1, wc = wid & 1, quad = lane >> 4, l16 = lane & 15;
    const int rowbase = blockIdx.x * 64;           // global BN row
    const int b = rowbase / kN, q0 = rowbase % kN; // batch / in-batch row

    f32x4 acc[2][4];
#pragma unroll
    for (int i = 0; i < 2; ++i)
#pragma unroll
        for (int ct = 0; ct < 4; ++ct) acc[i][ct] = (f32x4){0.f, 0.f, 0.f, 0.f};

#pragma unroll
    for (int k = 0; k < 4; ++k) {
        bf16x8 Af[2], Bf[4];
#pragma unroll
        for (int i = 0; i < 2; ++i)
            Af[i] = *(const bf16x8*)&h16[(size_t)(rowbase + wr * 32 + i * 16 + l16) * kH + k * 32 + quad * 8];
#pragma unroll
        for (int ct = 0; ct < 4; ++ct)
            Bf[ct] = *(const bf16x8*)&WT[(size_t)(wc * 64 + ct * 16 + l16) * kH + k * 32 + quad * 8];
#pragma unroll
        for (int i = 0; i < 2; ++i)
#pragma unroll
            for (int ct = 0; ct < 4; ++ct)
                acc[i][ct] = __builtin_amdgcn_mfma_f32_16x16x32_bf16(Af[i], Bf[ct], acc[i][ct], 0, 0, 0);
    }

    float bsr[4];
#pragma unroll
    for (int ct = 0; ct < 4; ++ct) bsr[ct] = bias[wc * 64 + ct * 16 + l16];

    f32x4 ss[2] = {(f32x4){0,0,0,0}, (f32x4){0,0,0,0}};
#pragma unroll
    for (int i = 0; i < 2; ++i)
#pragma unroll
        for (int ct = 0; ct < 4; ++ct)
#pragma unroll
            for (int r = 0; r < 4; ++r) {
                float v = acc[i][ct][r] + bsr[ct];
                acc[i][ct][r] = v;
                ss[i][r] += v * v;
            }
#pragma unroll
    for (int step = 1; step < 16; step <<= 1)
#pragma unroll
        for (int i = 0; i < 2; ++i)
#pragma unroll
            for (int r = 0; r < 4; ++r) ss[i][r] += __shfl_xor(ss[i][r], step);

    if (l16 == 0)
#pragma unroll
        for (int i = 0; i < 2; ++i)
#pragma unroll
            for (int r = 0; r < 4; ++r)
                ssb[wr * 32 + i * 16 + quad * 4 + r][wc] = ss[i][r];
    __syncthreads();

    // per-thread inv-norm for its 8 rows
    float invr[2][4];
#pragma unroll
    for (int i = 0; i < 2; ++i)
#pragma unroll
        for (int r = 0; r < 4; ++r) {
            const int pl = wr * 32 + i * 16 + quad * 4 + r;
            float s2 = ssb[pl][0] + ssb[pl][1];
            invr[i][r] = 1.f / fmaxf(sqrtf(s2), 1e-12f);
        }

    // LDS tiles: tr (raw, c-major) + trn (normalized, p-major)
#pragma unroll
    for (int i = 0; i < 2; ++i)
#pragma unroll
        for (int ct = 0; ct < 4; ++ct)
#pragma unroll
            for (int r = 0; r < 4; ++r) {
                const int pl = wr * 32 + i * 16 + quad * 4 + r;
                const int c = wc * 64 + ct * 16 + l16;
                const float v = acc[i][ct][r];
                tr[c * 72 + pl] = bf16bits(v);
                trn[pl * 136 + c] = bf16bits(v * invr[i][r]);
            }
    __syncthreads();

    // coalesced tT writeout: 128 c-rows x 64 q (raw t)
    ushort* tTb = tT16 + (size_t)b * kH * kN;
#pragma unroll
    for (int it = 0; it < 4; ++it) {
        int idx = tid + 256 * it;           // 0..1023
        int c = idx >> 3, ch = idx & 7;
        bf16x8 v = *(const bf16x8*)&tr[c * 72 + ch * 8];
        *(bf16x8*)&tTb[(size_t)c * kN + q0 + ch * 8] = v;
    }
    // coalesced tn writeout: 64 p-rows x 128 c (normalized)
#pragma unroll
    for (int it = 0; it < 4; ++it) {
        int idx = tid + 256 * it;           // 0..1023
        int p = idx >> 4, ch = idx & 15;
        bf16x8 v = *(const bf16x8*)&trn[p * 136 + ch * 8];
        *(bf16x8*)&tn16[(size_t)(rowbase + p) * kH + ch * 8] = v;
    }
}

// ---------------- fused aggregation: DMA-staged dbuf, 1 barrier/iter ----------------
// 512 thr = 8 waves (wp = wid>>2: p 32-halves; wq = wid&3: q 32-quarters of
// the 128 q-tile). grid (8 batches, kN/64 = 32 p-blocks). TQ/TT staged by
// global_load_lds (pre-swizzled source, linear dest).
__global__ __launch_bounds__(512, 2) void agg_kernel(
    const ushort* __restrict__ tn, const ushort* __restrict__ tT,
    const float* __restrict__ ew,
    ushort* __restrict__ hout, float* __restrict__ fout, int last)
{
    __shared__ char TQs[2][32768];   // [buf][128 q][256B], swz slot = c ^ (q&15)
    __shared__ char TTs[2][32768];   // [buf][128 c][256B], swz slot = c ^ (r&15)
    __shared__ char ews[8][2048];    // per-wave [32 p][64B] bf16, swz ((p&7)<<3)

    const int b = blockIdx.x, pbase = blockIdx.y * 64;
    const int tid = threadIdx.x, lane = tid & 63, wid = tid >> 6;
    const int wp = wid >> 2, wq = wid & 3;
    const int l31 = lane & 31, h = lane >> 5;

    const ushort* tb  = tn + (size_t)b * kN * kH;
    const ushort* tTb = tT + (size_t)b * kH * kN;
    const float*  ewb = ew + (size_t)b * kN * kN;

    char* myEw = &ews[wid][0];
    const int pbg = pbase + wp * 32;

    // tP (B-operand of swapped S, normalized rows): one-time scattered load
    bf16x8 tP[8];
#pragma unroll
    for (int m = 0; m < 8; ++m)
        tP[m] = *(const bf16x8*)&tb[(size_t)(pbg + l31) * kH + m * 16 + h * 8];

    f32x16 oacc[4];
#pragma unroll
    for (int ct = 0; ct < 4; ++ct)
#pragma unroll
        for (int r = 0; r < 16; ++r) oacc[ct][r] = 0.f;

    // DMA staging geometry: wave wid covers rows [16*wid, 16*wid+16) of TQ
    // and TT, 4 passes of 4 rows (64 lanes x 16B = 4 x 256B rows).
    // Lane l -> row r0 + (l>>4), slot (l&15); global source chunk is
    // (l&15) ^ (row&15), so LDS slot s of row r holds chunk s^(r&15) --
    // matching the read-side offset ((c*16) ^ ((r&15)<<4)).
    const int dRow = lane >> 4, dCh = lane & 15;
    // ew map: 8 lanes/row (f32x4), 8 rows/pass x 4 passes (32p x 32q per wave)
    const int ewR = lane >> 3, ewQ = lane & 7;

    f32x4 eC[4];

    auto issueTile = [&](int qb, int buf) {
#pragma unroll
        for (int p = 0; p < 4; ++p) {
            const int r0 = wid * 16 + p * 4;
            const int row = r0 + dRow;
            gload16(&tb [(size_t)(qb + row) * kH + ((dCh ^ (row & 15)) * 8)], &TQs[buf][r0 * 256]);
            gload16(&tTb[(size_t)row * kN + qb + ((dCh ^ (row & 15)) * 8)],  &TTs[buf][r0 * 256]);
        }
    };
    auto loadEw = [&](int qb) {
#pragma unroll
        for (int j = 0; j < 4; ++j)
            eC[j] = *(const f32x4*)&ewb[(size_t)(pbg + 8 * j + ewR) * kN + qb + wq * 32 + ewQ * 4];
    };

    // prologue: tile 0 + ew 0
    issueTile(0, 0);
    loadEw(0);
    __syncthreads();

    // scale S'[32p x 32q] by ew, pack bf16, half-swap (permlane) -> 2 A-frags
    auto buildFrags = [&](const f32x16& sa, const f32x16& sb, bf16x8* out2) {
        float sv[16];
#pragma unroll
        for (int g = 0; g < 4; ++g) {
            u32x2 ev = *(const u32x2*)&myEw[l31 * 64 + ((16 * g + 8 * h) ^ ((l31 & 7) << 3))];
            sv[4 * g + 0] = (sa[4 * g + 0] + sb[4 * g + 0]) * bf2f_lo(ev[0]);
            sv[4 * g + 1] = (sa[4 * g + 1] + sb[4 * g + 1]) * bf2f_hi(ev[0]);
            sv[4 * g + 2] = (sa[4 * g + 2] + sb[4 * g + 2]) * bf2f_lo(ev[1]);
            sv[4 * g + 3] = (sa[4 * g + 3] + sb[4 * g + 3]) * bf2f_hi(ev[1]);
        }
#pragma unroll
        for (int kk = 0; kk < 2; ++kk) {
            const int e0 = kk * 8;
            unsigned a0 = pk2(sv[e0 + 0], sv[e0 + 1]);
            unsigned a1 = pk2(sv[e0 + 2], sv[e0 + 3]);
            unsigned b0 = pk2(sv[e0 + 4], sv[e0 + 5]);
            unsigned b1 = pk2(sv[e0 + 6], sv[e0 + 7]);
            asm("v_permlane32_swap_b32 %0, %1" : "+v"(a0), "+v"(b0));
            asm("v_permlane32_swap_b32 %0, %1" : "+v"(a1), "+v"(b1));
            union { unsigned u[4]; bf16x8 v; } U;
            U.u[0] = a0;   // q-pair (8h+0, 8h+1)
            U.u[1] = a1;   // q-pair (8h+2, 8h+3)
            U.u[2] = b0;   // q-pair (8h+4, 8h+5)
            U.u[3] = b1;   // q-pair (8h+6, 8h+7)
            out2[kk] = U.v;
        }
    };

    for (int it = 0; it < 16; ++it) {
        const int buf = it & 1;

        // (1) publish ew(it) from eC regs (wave-local, lgkm-ordered)
#pragma unroll
        for (int j = 0; j < 4; ++j) {
            const int row = 8 * j + ewR;
            u32x2 w;
            w[0] = pk2(eC[j][0], eC[j][1]);
            w[1] = pk2(eC[j][2], eC[j][3]);
            *(u32x2*)&myEw[row * 64 + ((ewQ * 8) ^ ((row & 7) << 3))] = w;
        }

        // (2) issue next tile's DMA into the buffer freed by the last
        //     barrier + (3) next ew into eC — in flight across compute.
        if (it < 15) {
            issueTile((it + 1) * 128, buf ^ 1);
            loadEw((it + 1) * 128);
        }

        // (4) S-phase: s[q=32(wq)][p=32(wp)] = tnQ . tnP^T over d=128
        f32x16 s0a, s0b;
#pragma unroll
        for (int r = 0; r < 16; ++r) { s0a[r] = 0.f; s0b[r] = 0.f; }
        const int qrow = wq * 32 + l31;
        const int qswz = (qrow & 15) << 4;
#pragma unroll
        for (int m = 0; m < 8; ++m) {
            bf16x8 a = *(const bf16x8*)&TQs[buf][qrow * 256 + ((m * 32 + 16 * h) ^ qswz)];
            if (m & 1) s0b = __builtin_amdgcn_mfma_f32_32x32x16_bf16(a, tP[m], s0b, 0, 0, 0);
            else       s0a = __builtin_amdgcn_mfma_f32_32x32x16_bf16(a, tP[m], s0a, 0, 0, 0);
        }

        bf16x8 aw[2];
        buildFrags(s0a, s0b, aw);

        // O-phase: oacc[p][c] += S'[32p x 32q] @ t[32q x 128c]
#pragma unroll
        for (int kkt = 0; kkt < 2; ++kkt) {
#pragma unroll
            for (int ct = 0; ct < 4; ++ct) {
                const int crow = 32 * ct + l31;
                bf16x8 Bf = *(const bf16x8*)&TTs[buf][crow * 256 +
                              ((wq * 64 + kkt * 32 + 16 * h) ^ ((crow & 15) << 4))];
                oacc[ct] = __builtin_amdgcn_mfma_f32_32x32x16_bf16(aw[kkt], Bf, oacc[ct], 0, 0, 0);
            }
        }

        // (5) fence: drains DMA(it+1) + ew(it+1) (all issued ~2000cy ago)
        __syncthreads();
    }

    // ---- epilogue: reduce 4 wq partials in LDS (reuses TQ region), store ----
    float* OL = (float*)&TQs[0][0];   // [64][128] f32 = 32 KB
#pragma unroll
    for (int w = 0; w < 4; ++w) {
        if (wq == w) {
#pragma unroll
            for (int ct = 0; ct < 4; ++ct)
#pragma unroll
                for (int r = 0; r < 16; ++r) {
                    const int pl = wp * 32 + (r & 3) + 8 * (r >> 2) + 4 * h;
                    const int idx = pl * 128 + 32 * ct + l31;
                    if (w == 0) OL[idx] = oacc[ct][r];
                    else        OL[idx] += oacc[ct][r];
                }
        }
        __syncthreads();
    }

    {
        const int p = tid >> 3, cb = (tid & 7) * 16;
        const size_t gbase = (size_t)b * kN * kH + (size_t)(pbase + p) * kH + cb;
        if (!last) {
#pragma unroll
            for (int u = 0; u < 2; ++u) {
                bf16x8 o;
#pragma unroll
                for (int k = 0; k < 8; ++k)
                    o[k] = (short)bf16bits(fmaxf(OL[p * 128 + cb + u * 8 + k], 0.f));
                *(bf16x8*)&hout[gbase + u * 8] = o;
            }
        } else {
#pragma unroll
            for (int u = 0; u < 4; ++u) {
                f32x4 o;
#pragma unroll
                for (int k = 0; k < 4; ++k)
                    o[k] = OL[p * 128 + cb + u * 4 + k];
                *(f32x4*)&fout[gbase + u * 4] = o;
            }
        }
    }
}

extern "C" void kernel_launch(void* const* d_in, const int* in_sizes, int n_in,
                              void* d_out, int out_size, void* d_ws, size_t ws_size,
                              hipStream_t stream) {
    const float* x  = (const float*)d_in[0];
    const float* ew = (const float*)d_in[1];
    const float* W0 = (const float*)d_in[2];
    const float* b0 = (const float*)d_in[3];
    const float* W1 = (const float*)d_in[4];
    const float* b1 = (const float*)d_in[5];
    const float* W2 = (const float*)d_in[6];
    const float* b2 = (const float*)d_in[7];
    const float* bias[3] = {b0, b1, b2};

    const size_t nBNH = (size_t)kB * kN * kH;  // 2M
    ushort* h16  = (ushort*)d_ws;               // [B,N,H] bf16 (x, then relu h)
    ushort* tn16 = h16 + nBNH;                  // [B,N,H] bf16 normalized t
    ushort* tT16 = tn16 + nBNH;                 // [B,H,N] bf16 raw t, transposed
    ushort* WT   = tT16 + nBNH;                 // 3 x [H,D] bf16
    float*  out  = (float*)d_out;

    cvt_bf16_kernel<<<(int)(nBNH / 4 + 255) / 256, 256, 0, stream>>>(x, h16, (int)(nBNH / 4));
    cvt_wT_kernel<<<dim3(64, 3), 256, 0, stream>>>(W0, W1, W2, WT);

    for (int layer = 0; layer < 3; ++layer) {
        linear_tr_kernel<<<kB * kN / 64, 256, 0, stream>>>(
            h16, WT + (size_t)layer * kH * kH, bias[layer], tn16, tT16);
        agg_kernel<<<dim3(kB, kN / 64), 512, 0, stream>>>(
            tn16, tT16, ew, h16, out, layer == 2 ? 1 : 0);
    }
}